// Round 5
// baseline (207.235 us; speedup 1.0000x reference)
//
#include <hip/hip_runtime.h>
#include <hip/hip_bf16.h>

// B=2, N=2048, C=1024, H=16, hd=64, M=4096. bf16 MFMA path (threshold 2%).

typedef __attribute__((ext_vector_type(8))) short short8;
typedef __attribute__((ext_vector_type(4))) short short4v;
typedef __attribute__((ext_vector_type(4))) float float4v;
typedef __attribute__((ext_vector_type(4))) unsigned uint4v;

__device__ __forceinline__ unsigned short f2bf(float f) {   // RTNE
    unsigned u = __builtin_bit_cast(unsigned, f);
    return (unsigned short)((u + 0x7FFFu + ((u >> 16) & 1u)) >> 16);
}
// hardware packed f32->bf16 (RTNE), lo in low half
__device__ __forceinline__ unsigned cvtpk(float lo, float hi) {
    unsigned r;
    asm("v_cvt_pk_bf16_f32 %0, %1, %2" : "=v"(r) : "v"(lo), "v"(hi));
    return r;
}
__device__ __forceinline__ void gll16(const unsigned short* g, unsigned short* l) {
    __builtin_amdgcn_global_load_lds(
        (const __attribute__((address_space(1))) unsigned int*)g,
        (__attribute__((address_space(3))) unsigned int*)l, 16, 0, 0);
}

// ---------------- prep: ln1 (blocks 0..4095) + weight transposes.
__global__ __launch_bounds__(256) void prep(
    const float* __restrict__ x, const float* __restrict__ g1, const float* __restrict__ b1,
    const float* __restrict__ w_qk, const float* __restrict__ w_v,
    const float* __restrict__ w_proj, const float* __restrict__ g2,
    const float* __restrict__ b2,
    unsigned short* __restrict__ xn, unsigned short* __restrict__ wqkvT,
    unsigned short* __restrict__ wgT, float* __restrict__ u, float* __restrict__ w0) {
    __shared__ float sh[32 * 33];
    const int bid = blockIdx.x, tid = threadIdx.x;
    if (bid < 4096) {                       // ---- LN1 row
        const float4 v = reinterpret_cast<const float4*>(x + (size_t)bid * 1024)[tid];
        float s  = v.x + v.y + v.z + v.w;
        float sq = v.x * v.x + v.y * v.y + v.z * v.z + v.w * v.w;
#pragma unroll
        for (int off = 32; off >= 1; off >>= 1) {
            s  += __shfl_xor(s, off, 64);
            sq += __shfl_xor(sq, off, 64);
        }
        const int w = tid >> 6, lane = tid & 63;
        if (lane == 0) { sh[w] = s; sh[4 + w] = sq; }
        __syncthreads();
        s  = sh[0] + sh[1] + sh[2] + sh[3];
        sq = sh[4] + sh[5] + sh[6] + sh[7];
        const float mu = s * (1.f / 1024.f);
        const float rstd = rsqrtf(sq * (1.f / 1024.f) - mu * mu + 1e-5f);
        const float4 gv = reinterpret_cast<const float4*>(g1)[tid];
        const float4 bv = reinterpret_cast<const float4*>(b1)[tid];
        ushort4 o;
        o.x = f2bf((v.x - mu) * rstd * gv.x + bv.x);
        o.y = f2bf((v.y - mu) * rstd * gv.y + bv.y);
        o.z = f2bf((v.z - mu) * rstd * gv.z + bv.z);
        o.w = f2bf((v.w - mu) * rstd * gv.w + bv.w);
        *reinterpret_cast<ushort4*>(&xn[(size_t)bid * 1024 + tid * 4]) = o;
    } else {                                // ---- transpose f32[1024][Cc] -> bf16[Cc][1024]
        const float* in; unsigned short* out; int Cc, bx, by; bool doU = false;
        if (bid < 6144)      { int t = bid - 4096; in = w_qk;   out = wqkvT;               Cc = 2048; bx = t & 63; by = t >> 6; }
        else if (bid < 7168) { int t = bid - 6144; in = w_v;    out = wqkvT + 2048 * 1024; Cc = 1024; bx = t & 31; by = t >> 5; }
        else                 { int t = bid - 7168; in = w_proj; out = wgT; doU = true;     Cc = 1024; bx = t & 31; by = t >> 5; }
        const int c0 = bx * 32, r0 = by * 32;
        const int tx = tid & 31, ty = tid >> 5;
#pragma unroll
        for (int i = 0; i < 32; i += 8)
            sh[(ty + i) * 33 + tx] = in[(size_t)(r0 + ty + i) * Cc + c0 + tx];
        __syncthreads();
        // out col = original row index c = r0+tx
        const float scale = doU ? g2[r0 + tx] : 1.f;
        const float b2v   = doU ? b2[r0 + tx] : 0.f;
#pragma unroll
        for (int i = 0; i < 32; i += 8) {
            const float raw = sh[tx * 33 + ty + i];
            const float sc  = raw * scale;
            out[(size_t)(c0 + ty + i) * 1024 + r0 + tx] = f2bf(sc);
            if (doU) {
                float pu = sc, pw = raw * b2v;    // per-c contributions for j=c0+ty+i
#pragma unroll
                for (int off = 1; off <= 16; off <<= 1) {   // reduce over tx (32 lanes)
                    pu += __shfl_xor(pu, off, 64);
                    pw += __shfl_xor(pw, off, 64);
                }
                if (tx == 0) {
                    atomicAdd(&u[c0 + ty + i], pu);
                    atomicAdd(&w0[c0 + ty + i], pw);
                }
            }
        }
    }
}

// ---------------- GEMM1 v3: 128x128 tile, 512 thr / 8 waves (2m x 4n),
// BK=64, 3-DEEP LDS rotation + counted vmcnt (T4). With 2 buffers the
// per-step vmcnt(0) drain is semantically forced (next buffer must fully
// land at each barrier) — that was the flat-pipe stall (MfmaUtil 17%).
// 3 buffers: iter s reads buf s%3, stage(s+1) lands in (s+1)%3, stage(s+2)
// issued into (s+2)%3 and stays IN FLIGHT across the barrier. Each wave
// issues exactly 4 gll16 per stage -> wait vmcnt(4) at the barrier =
// stage(s+1) landed (all waves, lockstep issue order), stage(s+2) flying.
// LDS 96 KB -> 1 block/CU x 8 waves (m201 regime). Grid 24x32=768 = 3 exact
// rounds over 256 CUs.
__global__ __launch_bounds__(512) void gemm_qkv(const unsigned short* __restrict__ A,
                                                const unsigned short* __restrict__ Bt,
                                                unsigned short* __restrict__ qb,
                                                unsigned short* __restrict__ kb,
                                                unsigned short* __restrict__ vT) {
    __shared__ unsigned short As[3 * 128 * 64];   // 48 KB
    __shared__ unsigned short Bs[3 * 128 * 64];   // 48 KB
    const int tid = threadIdx.x, lane = tid & 63, w = tid >> 6;     // w 0..7
    const int wm = (w >> 2) * 64, wn = (w & 3) * 32;
    const int quad = lane >> 4, l16 = lane & 15;
    const int ls = lane >> 3, sg = lane & 7;
    const int m0 = blockIdx.y * 128, n0 = blockIdx.x * 128;

    float4v acc[4][2];
#pragma unroll
    for (int mi = 0; mi < 4; mi++)
#pragma unroll
        for (int ni = 0; ni < 2; ni++) acc[mi][ni] = float4v{0.f, 0.f, 0.f, 0.f};

    const int g = (sg ^ ls) * 8;
    // stage(t): each wave stages 16 rows of A and 16 rows of B (2+2 gll16)
#define STAGE_QKV(t)                                                                   \
    {                                                                                  \
        const int k0_ = (t) << 6, off_ = ((t) % 3) * 8192;                             \
        _Pragma("unroll")                                                              \
        for (int i = 0; i < 2; i++)                                                    \
            gll16(&A[(size_t)(m0 + w * 16 + i * 8 + ls) * 1024 + k0_ + g],             \
                  &As[off_ + (w * 16 + i * 8) * 64]);                                  \
        _Pragma("unroll")                                                              \
        for (int i = 0; i < 2; i++)                                                    \
            gll16(&Bt[(size_t)(n0 + w * 16 + i * 8 + ls) * 1024 + k0_ + g],            \
                  &Bs[off_ + (w * 16 + i * 8) * 64]);                                  \
    }

    STAGE_QKV(0);
    STAGE_QKV(1);

#pragma unroll 1
    for (int s = 0; s < 16; s++) {
        // stage(s) landed for all waves; stage(s+1)/(s+2) may stay in flight
        if (s < 15) asm volatile("s_waitcnt vmcnt(4)" ::: "memory");
        else        asm volatile("s_waitcnt vmcnt(0)" ::: "memory");
        __builtin_amdgcn_s_barrier();
        if (s + 2 < 16) STAGE_QKV(s + 2);   // into buf (s+2)%3 (dead since s-1)

        const unsigned short* Ac = As + (s % 3) * 8192;
        const unsigned short* Bc = Bs + (s % 3) * 8192;
#pragma unroll
        for (int ks = 0; ks < 2; ks++) {
            short8 af[4], bfr[2];
#pragma unroll
            for (int mi = 0; mi < 4; mi++) {
                const int r = wm + mi * 16 + l16;
                af[mi] = *reinterpret_cast<const short8*>(
                    &Ac[r * 64 + ((ks * 4 + quad) ^ (r & 7)) * 8]);
            }
#pragma unroll
            for (int ni = 0; ni < 2; ni++) {
                const int r = wn + ni * 16 + l16;
                bfr[ni] = *reinterpret_cast<const short8*>(
                    &Bc[r * 64 + ((ks * 4 + quad) ^ (r & 7)) * 8]);
            }
#pragma unroll
            for (int mi = 0; mi < 4; mi++)
#pragma unroll
                for (int ni = 0; ni < 2; ni++)
                    acc[mi][ni] = __builtin_amdgcn_mfma_f32_16x16x32_bf16(
                        af[mi], bfr[ni], acc[mi][ni], 0, 0, 0);
        }
    }
#undef STAGE_QKV

    const float QSCALE = 0.125f * 1.4426950408889634f;  // hd^-0.5 * log2(e)
#pragma unroll
    for (int mi = 0; mi < 4; mi++) {
        const int row0 = m0 + wm + mi * 16 + quad * 4;
        const int b = row0 >> 11, nq = row0 & 2047;
#pragma unroll
        for (int ni = 0; ni < 2; ni++) {
            const int col = n0 + wn + ni * 16 + l16;
            if (col < 1024) {             // q: [bh][n][d]
                const int h = col >> 6, d = col & 63;
#pragma unroll
                for (int r = 0; r < 4; r++)
                    qb[(((size_t)b * 16 + h) * 2048 + nq + r) * 64 + d] =
                        f2bf(acc[mi][ni][r] * QSCALE);
            } else if (col < 2048) {      // k: [bh][n][d]
                const int c = col - 1024, h = c >> 6, d = c & 63;
#pragma unroll
                for (int r = 0; r < 4; r++)
                    kb[(((size_t)b * 16 + h) * 2048 + nq + r) * 64 + d] = f2bf(acc[mi][ni][r]);
            } else {                      // v^T: [bh][d][n], 4 consecutive keys -> 8B store
                const int c = col - 2048, h = c >> 6, d = c & 63;
                const short4v sv = {(short)f2bf(acc[mi][ni][0]), (short)f2bf(acc[mi][ni][1]),
                                    (short)f2bf(acc[mi][ni][2]), (short)f2bf(acc[mi][ni][3])};
                *reinterpret_cast<short4v*>(
                    &vT[(((size_t)b * 16 + h) * 64 + d) * 2048 + nq]) = sv;
            }
        }
    }
}

// ---------------- flash attention v10 = R2's best-measured v7 (48.4 us:
// 512 thr / 8 waves, key-split wave pairs, 2-dbuf 32 KB LDS, 1 barrier/tile)
// + R4's proven XCD-locality grid (bh fastest-varying: FETCH 69.7->12.3 MB).
// Five structural variants all landed 48-51 us -> flash is chain-bound;
// keep the best and stop poking.
__global__ __launch_bounds__(512, 4) void flash_attn(const unsigned short* __restrict__ qbuf,
                                                     const unsigned short* __restrict__ kb,
                                                     const unsigned short* __restrict__ vT,
                                                     unsigned short* __restrict__ attn,
                                                     float2* __restrict__ part) {
    __shared__ __align__(16) unsigned short KV[4][64 * 64];  // [0..1]=K dbuf [2..3]=V dbuf, 32 KB
    __shared__ float lsh[4][2][64];                          // l partials kh=1 -> kh=0, 2 KB
    const int tid = threadIdx.x, lane = tid & 63, w = tid >> 6;   // w 0..7
    const int wq = w & 3, kh = w >> 2;
    const int quad = lane >> 4, l16 = lane & 15;
    const int ls = lane >> 3, sg = lane & 7;
    const int bh = blockIdx.x, q0 = blockIdx.y * 128;
    const size_t nbase = (size_t)bh * 2048;

    // K staging: phys row pr holds actual key ka = [bit5][quad(2b)][cb&1][reg]
    const int pr = w * 8 + ls;
    const int srow = (pr & 32) | ((pr & 12) << 1) | ((pr & 16) >> 2) | (pr & 3);
    const int sgran = (sg ^ ls) << 3;

    short8 bq[2][2];   // Q as B-operand, q = q0 + wq*32 + q2*16 + l16
#pragma unroll
    for (int q2 = 0; q2 < 2; q2++)
#pragma unroll
        for (int ks = 0; ks < 2; ks++)
            bq[q2][ks] = *reinterpret_cast<const short8*>(
                &qbuf[(nbase + q0 + wq * 32 + q2 * 16 + l16) * 64 + ks * 32 + quad * 8]);

    float l_part[2] = {0.f, 0.f};
    float4v o_acc[2][4];   // o_acc[q2][db]: d = db*16+quad*4+reg, q = l16 (partial: kh half)
#pragma unroll
    for (int q2 = 0; q2 < 2; q2++)
#pragma unroll
        for (int db = 0; db < 4; db++) o_acc[q2][db] = float4v{0.f, 0.f, 0.f, 0.f};

    // stage tile 0 (K permuted; V rows d = w*8+ls)
    gll16(&kb[(nbase + srow) * 64 + sgran], &KV[0][w * 8 * 64]);
    gll16(&vT[((size_t)bh * 64 + w * 8 + ls) * 2048 + sgran], &KV[2][w * 8 * 64]);

#pragma unroll 1
    for (int s = 0; s < 32; s++) {
        __syncthreads();                    // drains tile-s DMA
        if (s + 1 < 32) {                   // stage tile s+1 (drained next barrier)
            const int ktn = (s + 1) << 6, buf = (s + 1) & 1;
            gll16(&kb[(nbase + ktn + srow) * 64 + sgran], &KV[buf][w * 8 * 64]);
            gll16(&vT[((size_t)bh * 64 + w * 8 + ls) * 2048 + ktn + sgran],
                  &KV[2 + buf][w * 8 * 64]);
        }
        const unsigned short* Kc = KV[s & 1];
        const unsigned short* Vc = KV[2 + (s & 1)];

        // this wave's 32-key half: phys rows kh*32 + cc*16 + l16
        short8 kf[2][2];
#pragma unroll
        for (int ks = 0; ks < 2; ks++)
#pragma unroll
            for (int cc = 0; cc < 2; cc++) {
                const int r = kh * 32 + cc * 16 + l16;
                kf[ks][cc] = *reinterpret_cast<const short8*>(
                    &Kc[r * 64 + ((ks * 4 + quad) ^ (r & 7)) * 8]);
            }
        // V^T A-fragments for this key half: A[d=db*16+l16][k = kh*32 + quad*8 + j]
        short8 va[4];
#pragma unroll
        for (int db = 0; db < 4; db++) {
            const int r = db * 16 + l16;
            va[db] = *reinterpret_cast<const short8*>(
                &Vc[r * 64 + ((kh * 4 + quad) ^ (r & 7)) * 8]);
        }

#pragma unroll
        for (int q2 = 0; q2 < 2; q2++) {
            float4v s_acc[2];
#pragma unroll
            for (int cc = 0; cc < 2; cc++) s_acc[cc] = float4v{0.f, 0.f, 0.f, 0.f};
            __builtin_amdgcn_s_setprio(1);
#pragma unroll
            for (int ks = 0; ks < 2; ks++)
#pragma unroll
                for (int cc = 0; cc < 2; cc++)
                    s_acc[cc] = __builtin_amdgcn_mfma_f32_16x16x32_bf16(
                        kf[ks][cc], bq[q2][ks], s_acc[cc], 0, 0, 0);
            __builtin_amdgcn_s_setprio(0);

            // fixed-max softmax: p = 2^s. Permuted K rows make the pack
            // register-local: actual key = kh*32 + quad*8 + cc*4 + reg.
            float ls2 = 0.f;
            float p[8];
#pragma unroll
            for (int cc = 0; cc < 2; cc++)
#pragma unroll
                for (int r = 0; r < 4; r++) {
                    const float pv = __builtin_amdgcn_exp2f(s_acc[cc][r]);
                    p[cc * 4 + r] = pv;
                    ls2 += pv;
                }
            uint4v pd;
            pd.x = cvtpk(p[0], p[1]); pd.y = cvtpk(p[2], p[3]);
            pd.z = cvtpk(p[4], p[5]); pd.w = cvtpk(p[6], p[7]);
            const short8 pb = __builtin_bit_cast(short8, pd);
            l_part[q2] += ls2;
            __builtin_amdgcn_s_setprio(1);
#pragma unroll
            for (int db = 0; db < 4; db++)
                o_acc[q2][db] = __builtin_amdgcn_mfma_f32_16x16x32_bf16(
                    va[db], pb, o_acc[q2][db], 0, 0, 0);
            __builtin_amdgcn_s_setprio(0);
        }
    }

    // ---- combine key halves through LDS (K/V buffers are dead now).
    __syncthreads();                        // all waves done reading KV
    float* osh = reinterpret_cast<float*>(KV);   // 8192 floats = 32 KB exactly
    const int swz = (l16 & 7) << 2;              // 16B-granule XOR to spread banks
    if (kh == 1) {
#pragma unroll
        for (int q2 = 0; q2 < 2; q2++)
#pragma unroll
            for (int db = 0; db < 4; db++) {
                const int base = (wq * 32 + q2 * 16 + l16) * 64 + db * 16 + quad * 4;
                *reinterpret_cast<float4v*>(&osh[base ^ swz]) = o_acc[q2][db];
            }
        lsh[wq][0][lane] = l_part[0];
        lsh[wq][1][lane] = l_part[1];
    }
    __syncthreads();
    if (kh == 0) {
        const int b = bh >> 4, h = bh & 15;
#pragma unroll
        for (int q2 = 0; q2 < 2; q2++) {
            float lr = l_part[q2] + lsh[wq][q2][lane];
            lr += __shfl_xor(lr, 16, 64);
            lr += __shfl_xor(lr, 32, 64);
            const float inv = 1.f / lr;
            const int grow = b * 2048 + q0 + wq * 32 + q2 * 16 + l16;
            float sum = 0.f, s2 = 0.f;
#pragma unroll
            for (int db = 0; db < 4; db++) {
                const int base = (wq * 32 + q2 * 16 + l16) * 64 + db * 16 + quad * 4;
                const float4v oh = *reinterpret_cast<const float4v*>(&osh[base ^ swz]);
                const float o0 = (o_acc[q2][db][0] + oh[0]) * inv;
                const float o1 = (o_acc[q2][db][1] + oh[1]) * inv;
                const float o2 = (o_acc[q2][db][2] + oh[2]) * inv;
                const float o3 = (o_acc[q2][db][3] + oh[3]) * inv;
                const ushort4 st = {f2bf(o0), f2bf(o1), f2bf(o2), f2bf(o3)};
                *reinterpret_cast<ushort4*>(
                    &attn[(size_t)grow * 1024 + h * 64 + db * 16 + quad * 4]) = st;
                sum += (o0 + o1) + (o2 + o3);
                s2  += (o0 * o0 + o1 * o1) + (o2 * o2 + o3 * o3);
            }
            sum += __shfl_xor(sum, 16, 64); sum += __shfl_xor(sum, 32, 64);
            s2  += __shfl_xor(s2, 16, 64);  s2  += __shfl_xor(s2, 32, 64);
            if (quad == 0) part[(size_t)grow * 16 + h] = float2{sum, s2};
        }
    }
}

// ---------------- GEMM2: attn(bf16,raw) @ Wg^T, LN2 + rowstats fused.
// Tile 128(m) x 64(n) -> grid 512 = 2 blocks/CU.
__global__ __launch_bounds__(256) void gemm_proj(const unsigned short* __restrict__ A,
                                                 const unsigned short* __restrict__ Bt,
                                                 const float2* __restrict__ part,
                                                 const float* __restrict__ u,
                                                 const float* __restrict__ w0,
                                                 const float* __restrict__ bias,
                                                 float* __restrict__ out) {
    __shared__ unsigned short As[2 * 128 * 64];   // 32 KB
    __shared__ unsigned short Bs[2 * 64 * 64];    // 16 KB
    __shared__ float2 rstat_s[128];
    const int tid = threadIdx.x, lane = tid & 63, w = tid >> 6;
    const int quad = lane >> 4, l16 = lane & 15;
    const int ls = lane >> 3, sg = lane & 7;
    const int m0 = blockIdx.y * 128, n0 = blockIdx.x * 64;
    {   // rowstats for this block's 128 rows: 2 threads/row, 8 heads each
        const int rloc = tid >> 1, half = tid & 1;
        const float4* p4 = reinterpret_cast<const float4*>(part);
        float s = 0.f, s2 = 0.f;
#pragma unroll
        for (int j = 0; j < 4; j++) {
            const float4 p = p4[(size_t)(m0 + rloc) * 8 + half * 4 + j];
            s += p.x + p.z; s2 += p.y + p.w;
        }
        s  += __shfl_xor(s, 1, 64);
        s2 += __shfl_xor(s2, 1, 64);
        if (!half) {
            const float mu = s * (1.f / 1024.f);
            const float rstd = rsqrtf(s2 * (1.f / 1024.f) - mu * mu + 1e-5f);
            rstat_s[rloc] = float2{rstd, mu * rstd};
        }
    }   // ordered before use by the K-loop's first __syncthreads()

    float4v acc[2][4];
#pragma unroll
    for (int mi = 0; mi < 2; mi++)
#pragma unroll
        for (int ni = 0; ni < 4; ni++) acc[mi][ni] = float4v{0.f, 0.f, 0.f, 0.f};

    const int g = (sg ^ ls) * 8;
    // stage step 0
#pragma unroll
    for (int i = 0; i < 4; i++)
        gll16(&A[(size_t)(m0 + w * 32 + i * 8 + ls) * 1024 + g], &As[(w * 32 + i * 8) * 64]);
#pragma unroll
    for (int i = 0; i < 2; i++)
        gll16(&Bt[(size_t)(n0 + w * 16 + i * 8 + ls) * 1024 + g], &Bs[(w * 16 + i * 8) * 64]);

#pragma unroll 1
    for (int s = 0; s < 16; s++) {
        __syncthreads();
        if (s + 1 < 16) {
            const int k0 = (s + 1) << 6;
            unsigned short* Ad = As + (((s + 1) & 1) << 13);
            unsigned short* Bd = Bs + (((s + 1) & 1) << 12);
#pragma unroll
            for (int i = 0; i < 4; i++)
                gll16(&A[(size_t)(m0 + w * 32 + i * 8 + ls) * 1024 + k0 + g],
                      &Ad[(w * 32 + i * 8) * 64]);
#pragma unroll
            for (int i = 0; i < 2; i++)
                gll16(&Bt[(size_t)(n0 + w * 16 + i * 8 + ls) * 1024 + k0 + g],
                      &Bd[(w * 16 + i * 8) * 64]);
        }
        const unsigned short* Ac = As + ((s & 1) << 13);
        const unsigned short* Bc = Bs + ((s & 1) << 12);
#pragma unroll
        for (int ks = 0; ks < 2; ks++) {
            short8 af[2], bfr[4];
#pragma unroll
            for (int mi = 0; mi < 2; mi++) {
                const int r = w * 32 + mi * 16 + l16;
                af[mi] = *reinterpret_cast<const short8*>(
                    &Ac[r * 64 + ((ks * 4 + quad) ^ (r & 7)) * 8]);
            }
#pragma unroll
            for (int ni = 0; ni < 4; ni++) {
                const int r = ni * 16 + l16;
                bfr[ni] = *reinterpret_cast<const short8*>(
                    &Bc[r * 64 + ((ks * 4 + quad) ^ (r & 7)) * 8]);
            }
#pragma unroll
            for (int mi = 0; mi < 2; mi++)
#pragma unroll
                for (int ni = 0; ni < 4; ni++)
                    acc[mi][ni] = __builtin_amdgcn_mfma_f32_16x16x32_bf16(
                        af[mi], bfr[ni], acc[mi][ni], 0, 0, 0);
        }
    }

#pragma unroll
    for (int mi = 0; mi < 2; mi++) {
        const int rl0 = w * 32 + mi * 16 + quad * 4;
        float2 rs[4];
#pragma unroll
        for (int r = 0; r < 4; r++) rs[r] = rstat_s[rl0 + r];
#pragma unroll
        for (int ni = 0; ni < 4; ni++) {
            const int col = n0 + ni * 16 + l16;
            const float uu = u[col], ww = w0[col] + bias[col];
#pragma unroll
            for (int r = 0; r < 4; r++)
                out[(size_t)(m0 + rl0 + r) * 1024 + col] =
                    fmaf(rs[r].x, acc[mi][ni][r], ww - rs[r].y * uu);
        }
    }
}

extern "C" void kernel_launch(void* const* d_in, const int* in_sizes, int n_in,
                              void* d_out, int out_size, void* d_ws, size_t ws_size,
                              hipStream_t stream) {
    const float* x      = (const float*)d_in[0];
    const float* ln1_g  = (const float*)d_in[1];
    const float* ln1_b  = (const float*)d_in[2];
    const float* w_qk   = (const float*)d_in[3];
    const float* w_v    = (const float*)d_in[4];
    const float* ln2_g  = (const float*)d_in[5];
    const float* ln2_b  = (const float*)d_in[6];
    const float* w_proj = (const float*)d_in[7];
    const float* b_proj = (const float*)d_in[8];
    float* out = (float*)d_out;

    char* ws = (char*)d_ws;
    unsigned short* xn      = (unsigned short*)(ws + 0);         // 8MB  4096x1024 bf16
    unsigned short* wqkvT   = (unsigned short*)(ws + 8388608);   // 6MB  3072x1024 bf16
    unsigned short* wgT     = (unsigned short*)(ws + 14680064);  // 2MB  1024x1024 bf16 (g2-scaled w_proj^T)
    unsigned short* qbuf    = (unsigned short*)(ws + 16777216);  // 8MB  [32][2048][64]
    unsigned short* kbuf    = (unsigned short*)(ws + 25165824);  // 8MB  [32][2048][64]
    unsigned short* vTbuf   = (unsigned short*)(ws + 33554432);  // 8MB  [32][64][2048]
    unsigned short* attn    = (unsigned short*)(ws + 41943040);  // 8MB  4096x1024 bf16 (raw, pre-LN2)
    float2*         part    = (float2*)(ws + 50331648);          // 512KB [4096][16]
    float*          u       = (float*)(ws + 50888704);           // 4KB
    float*          w0      = (float*)(ws + 50892800);           // 4KB

    hipMemsetAsync(ws + 50888704, 0, 8192, stream);              // zero u + w0
    prep<<<8192, 256, 0, stream>>>(x, ln1_g, ln1_b, w_qk, w_v, w_proj, ln2_g, ln2_b,
                                   xn, wqkvT, wgT, u, w0);
    gemm_qkv<<<dim3(24, 32), 512, 0, stream>>>(xn, wqkvT, qbuf, kbuf, vTbuf);
    flash_attn<<<dim3(32, 16), 512, 0, stream>>>(qbuf, kbuf, vTbuf, attn, part);
    gemm_proj<<<dim3(16, 32), 256, 0, stream>>>(attn, wgT, part, u, w0, b_proj, out);
}

// Round 7
// 186.782 us; speedup vs baseline: 1.1095x; 1.1095x over previous
//
#include <hip/hip_runtime.h>
#include <hip/hip_bf16.h>

// B=2, N=2048, C=1024, H=16, hd=64, M=4096. bf16 MFMA path (threshold 2%).

typedef __attribute__((ext_vector_type(8))) short short8;
typedef __attribute__((ext_vector_type(4))) short short4v;
typedef __attribute__((ext_vector_type(4))) float float4v;
typedef __attribute__((ext_vector_type(4))) unsigned uint4v;

__device__ __forceinline__ unsigned short f2bf(float f) {   // RTNE
    unsigned u = __builtin_bit_cast(unsigned, f);
    return (unsigned short)((u + 0x7FFFu + ((u >> 16) & 1u)) >> 16);
}
// hardware packed f32->bf16 (RTNE), lo in low half
__device__ __forceinline__ unsigned cvtpk(float lo, float hi) {
    unsigned r;
    asm("v_cvt_pk_bf16_f32 %0, %1, %2" : "=v"(r) : "v"(lo), "v"(hi));
    return r;
}
__device__ __forceinline__ void gll16(const unsigned short* g, unsigned short* l) {
    __builtin_amdgcn_global_load_lds(
        (const __attribute__((address_space(1))) unsigned int*)g,
        (__attribute__((address_space(3))) unsigned int*)l, 16, 0, 0);
}

// ---------------- prep: ln1 (blocks 0..4095) + weight transposes.
__global__ __launch_bounds__(256) void prep(
    const float* __restrict__ x, const float* __restrict__ g1, const float* __restrict__ b1,
    const float* __restrict__ w_qk, const float* __restrict__ w_v,
    const float* __restrict__ w_proj, const float* __restrict__ g2,
    const float* __restrict__ b2,
    unsigned short* __restrict__ xn, unsigned short* __restrict__ wqkvT,
    unsigned short* __restrict__ wgT, float* __restrict__ u, float* __restrict__ w0) {
    __shared__ float sh[32 * 33];
    const int bid = blockIdx.x, tid = threadIdx.x;
    if (bid < 4096) {                       // ---- LN1 row
        const float4 v = reinterpret_cast<const float4*>(x + (size_t)bid * 1024)[tid];
        float s  = v.x + v.y + v.z + v.w;
        float sq = v.x * v.x + v.y * v.y + v.z * v.z + v.w * v.w;
#pragma unroll
        for (int off = 32; off >= 1; off >>= 1) {
            s  += __shfl_xor(s, off, 64);
            sq += __shfl_xor(sq, off, 64);
        }
        const int w = tid >> 6, lane = tid & 63;
        if (lane == 0) { sh[w] = s; sh[4 + w] = sq; }
        __syncthreads();
        s  = sh[0] + sh[1] + sh[2] + sh[3];
        sq = sh[4] + sh[5] + sh[6] + sh[7];
        const float mu = s * (1.f / 1024.f);
        const float rstd = rsqrtf(sq * (1.f / 1024.f) - mu * mu + 1e-5f);
        const float4 gv = reinterpret_cast<const float4*>(g1)[tid];
        const float4 bv = reinterpret_cast<const float4*>(b1)[tid];
        ushort4 o;
        o.x = f2bf((v.x - mu) * rstd * gv.x + bv.x);
        o.y = f2bf((v.y - mu) * rstd * gv.y + bv.y);
        o.z = f2bf((v.z - mu) * rstd * gv.z + bv.z);
        o.w = f2bf((v.w - mu) * rstd * gv.w + bv.w);
        *reinterpret_cast<ushort4*>(&xn[(size_t)bid * 1024 + tid * 4]) = o;
    } else {                                // ---- transpose f32[1024][Cc] -> bf16[Cc][1024]
        const float* in; unsigned short* out; int Cc, bx, by; bool doU = false;
        if (bid < 6144)      { int t = bid - 4096; in = w_qk;   out = wqkvT;               Cc = 2048; bx = t & 63; by = t >> 6; }
        else if (bid < 7168) { int t = bid - 6144; in = w_v;    out = wqkvT + 2048 * 1024; Cc = 1024; bx = t & 31; by = t >> 5; }
        else                 { int t = bid - 7168; in = w_proj; out = wgT; doU = true;     Cc = 1024; bx = t & 31; by = t >> 5; }
        const int c0 = bx * 32, r0 = by * 32;
        const int tx = tid & 31, ty = tid >> 5;
#pragma unroll
        for (int i = 0; i < 32; i += 8)
            sh[(ty + i) * 33 + tx] = in[(size_t)(r0 + ty + i) * Cc + c0 + tx];
        __syncthreads();
        // out col = original row index c = r0+tx
        const float scale = doU ? g2[r0 + tx] : 1.f;
        const float b2v   = doU ? b2[r0 + tx] : 0.f;
#pragma unroll
        for (int i = 0; i < 32; i += 8) {
            const float raw = sh[tx * 33 + ty + i];
            const float sc  = raw * scale;
            out[(size_t)(c0 + ty + i) * 1024 + r0 + tx] = f2bf(sc);
            if (doU) {
                float pu = sc, pw = raw * b2v;    // per-c contributions for j=c0+ty+i
#pragma unroll
                for (int off = 1; off <= 16; off <<= 1) {   // reduce over tx (32 lanes)
                    pu += __shfl_xor(pu, off, 64);
                    pw += __shfl_xor(pw, off, 64);
                }
                if (tx == 0) {
                    atomicAdd(&u[c0 + ty + i], pu);
                    atomicAdd(&w0[c0 + ty + i], pw);
                }
            }
        }
    }
}

// ---------------- GEMM1 v4: 128(m) x 192(n) tile, 512 thr / 8 waves (2m x 4n,
// acc 4x3), BK=64, 2-dbuf + __syncthreads (the only schedule that has ever
// paid here). LDS 80 KB -> 2 blocks/CU; grid 16x32 = 512 = EXACTLY 2/CU,
// uniform (R2's 768-block grid ran its last 256 blocks at 1/CU with no
// overlap partner). Counted-vmcnt variants (R5: 56.3 us) are dead — coarse
// loops at low block-residency never benefit (regime-gate lesson, twice).
__global__ __launch_bounds__(512, 2) void gemm_qkv(const unsigned short* __restrict__ A,
                                                   const unsigned short* __restrict__ Bt,
                                                   unsigned short* __restrict__ qb,
                                                   unsigned short* __restrict__ kb,
                                                   unsigned short* __restrict__ vT) {
    __shared__ unsigned short As[2 * 128 * 64];   // 32 KB
    __shared__ unsigned short Bs[2 * 192 * 64];   // 48 KB
    const int tid = threadIdx.x, lane = tid & 63, w = tid >> 6;     // w 0..7
    const int wm = (w >> 2) * 64, wn = (w & 3) * 48;
    const int quad = lane >> 4, l16 = lane & 15;
    const int ls = lane >> 3, sg = lane & 7;
    const int m0 = blockIdx.y * 128, n0 = blockIdx.x * 192;

    float4v acc[4][3];
#pragma unroll
    for (int mi = 0; mi < 4; mi++)
#pragma unroll
        for (int ni = 0; ni < 3; ni++) acc[mi][ni] = float4v{0.f, 0.f, 0.f, 0.f};

    const int g = (sg ^ ls) * 8;
    // stage step 0: per wave 16 A-rows (2 gll16) + 24 B-rows (3 gll16)
#pragma unroll
    for (int i = 0; i < 2; i++)
        gll16(&A[(size_t)(m0 + w * 16 + i * 8 + ls) * 1024 + g], &As[(w * 16 + i * 8) * 64]);
#pragma unroll
    for (int i = 0; i < 3; i++)
        gll16(&Bt[(size_t)(n0 + w * 24 + i * 8 + ls) * 1024 + g], &Bs[(w * 24 + i * 8) * 64]);

#pragma unroll 1
    for (int s = 0; s < 16; s++) {
        __syncthreads();
        if (s + 1 < 16) {                   // stage step s+1 (overlaps compute(s))
            const int k0 = (s + 1) << 6;
            unsigned short* Ad = As + (((s + 1) & 1) << 13);
            unsigned short* Bd = Bs + (((s + 1) & 1) * 12288);
#pragma unroll
            for (int i = 0; i < 2; i++)
                gll16(&A[(size_t)(m0 + w * 16 + i * 8 + ls) * 1024 + k0 + g],
                      &Ad[(w * 16 + i * 8) * 64]);
#pragma unroll
            for (int i = 0; i < 3; i++)
                gll16(&Bt[(size_t)(n0 + w * 24 + i * 8 + ls) * 1024 + k0 + g],
                      &Bd[(w * 24 + i * 8) * 64]);
        }
        const unsigned short* Ac = As + ((s & 1) << 13);
        const unsigned short* Bc = Bs + ((s & 1) * 12288);
#pragma unroll
        for (int ks = 0; ks < 2; ks++) {
            short8 af[4], bfr[3];
#pragma unroll
            for (int mi = 0; mi < 4; mi++) {
                const int r = wm + mi * 16 + l16;
                af[mi] = *reinterpret_cast<const short8*>(
                    &Ac[r * 64 + ((ks * 4 + quad) ^ (r & 7)) * 8]);
            }
#pragma unroll
            for (int ni = 0; ni < 3; ni++) {
                const int r = wn + ni * 16 + l16;
                bfr[ni] = *reinterpret_cast<const short8*>(
                    &Bc[r * 64 + ((ks * 4 + quad) ^ (r & 7)) * 8]);
            }
#pragma unroll
            for (int mi = 0; mi < 4; mi++)
#pragma unroll
                for (int ni = 0; ni < 3; ni++)
                    acc[mi][ni] = __builtin_amdgcn_mfma_f32_16x16x32_bf16(
                        af[mi], bfr[ni], acc[mi][ni], 0, 0, 0);
        }
    }

    const float QSCALE = 0.125f * 1.4426950408889634f;  // hd^-0.5 * log2(e)
#pragma unroll
    for (int mi = 0; mi < 4; mi++) {
        const int row0 = m0 + wm + mi * 16 + quad * 4;
        const int b = row0 >> 11, nq = row0 & 2047;
#pragma unroll
        for (int ni = 0; ni < 3; ni++) {
            const int col = n0 + wn + ni * 16 + l16;
            if (col < 1024) {             // q: [bh][n][d]
                const int h = col >> 6, d = col & 63;
#pragma unroll
                for (int r = 0; r < 4; r++)
                    qb[(((size_t)b * 16 + h) * 2048 + nq + r) * 64 + d] =
                        f2bf(acc[mi][ni][r] * QSCALE);
            } else if (col < 2048) {      // k: [bh][n][d]
                const int c = col - 1024, h = c >> 6, d = c & 63;
#pragma unroll
                for (int r = 0; r < 4; r++)
                    kb[(((size_t)b * 16 + h) * 2048 + nq + r) * 64 + d] = f2bf(acc[mi][ni][r]);
            } else {                      // v^T: [bh][d][n], 4 consecutive keys -> 8B store
                const int c = col - 2048, h = c >> 6, d = c & 63;
                const short4v sv = {(short)f2bf(acc[mi][ni][0]), (short)f2bf(acc[mi][ni][1]),
                                    (short)f2bf(acc[mi][ni][2]), (short)f2bf(acc[mi][ni][3])};
                *reinterpret_cast<short4v*>(
                    &vT[(((size_t)b * 16 + h) * 64 + d) * 2048 + nq]) = sv;
            }
        }
    }
}

// ---------------- flash attention v10 (best measured: 48.4 us schedule +
// FETCH 12 MB grid): 512 thr / 8 waves, key-split wave pairs, 2-dbuf 32 KB
// LDS, 1 barrier/tile, bh fastest-varying for XCD/L2 locality. Unchanged.
__global__ __launch_bounds__(512, 4) void flash_attn(const unsigned short* __restrict__ qbuf,
                                                     const unsigned short* __restrict__ kb,
                                                     const unsigned short* __restrict__ vT,
                                                     unsigned short* __restrict__ attn,
                                                     float2* __restrict__ part) {
    __shared__ __align__(16) unsigned short KV[4][64 * 64];  // [0..1]=K dbuf [2..3]=V dbuf, 32 KB
    __shared__ float lsh[4][2][64];                          // l partials kh=1 -> kh=0, 2 KB
    const int tid = threadIdx.x, lane = tid & 63, w = tid >> 6;   // w 0..7
    const int wq = w & 3, kh = w >> 2;
    const int quad = lane >> 4, l16 = lane & 15;
    const int ls = lane >> 3, sg = lane & 7;
    const int bh = blockIdx.x, q0 = blockIdx.y * 128;
    const size_t nbase = (size_t)bh * 2048;

    // K staging: phys row pr holds actual key ka = [bit5][quad(2b)][cb&1][reg]
    const int pr = w * 8 + ls;
    const int srow = (pr & 32) | ((pr & 12) << 1) | ((pr & 16) >> 2) | (pr & 3);
    const int sgran = (sg ^ ls) << 3;

    short8 bq[2][2];   // Q as B-operand, q = q0 + wq*32 + q2*16 + l16
#pragma unroll
    for (int q2 = 0; q2 < 2; q2++)
#pragma unroll
        for (int ks = 0; ks < 2; ks++)
            bq[q2][ks] = *reinterpret_cast<const short8*>(
                &qbuf[(nbase + q0 + wq * 32 + q2 * 16 + l16) * 64 + ks * 32 + quad * 8]);

    float l_part[2] = {0.f, 0.f};
    float4v o_acc[2][4];   // o_acc[q2][db]: d = db*16+quad*4+reg, q = l16 (partial: kh half)
#pragma unroll
    for (int q2 = 0; q2 < 2; q2++)
#pragma unroll
        for (int db = 0; db < 4; db++) o_acc[q2][db] = float4v{0.f, 0.f, 0.f, 0.f};

    // stage tile 0 (K permuted; V rows d = w*8+ls)
    gll16(&kb[(nbase + srow) * 64 + sgran], &KV[0][w * 8 * 64]);
    gll16(&vT[((size_t)bh * 64 + w * 8 + ls) * 2048 + sgran], &KV[2][w * 8 * 64]);

#pragma unroll 1
    for (int s = 0; s < 32; s++) {
        __syncthreads();                    // drains tile-s DMA
        if (s + 1 < 32) {                   // stage tile s+1 (drained next barrier)
            const int ktn = (s + 1) << 6, buf = (s + 1) & 1;
            gll16(&kb[(nbase + ktn + srow) * 64 + sgran], &KV[buf][w * 8 * 64]);
            gll16(&vT[((size_t)bh * 64 + w * 8 + ls) * 2048 + ktn + sgran],
                  &KV[2 + buf][w * 8 * 64]);
        }
        const unsigned short* Kc = KV[s & 1];
        const unsigned short* Vc = KV[2 + (s & 1)];

        // this wave's 32-key half: phys rows kh*32 + cc*16 + l16
        short8 kf[2][2];
#pragma unroll
        for (int ks = 0; ks < 2; ks++)
#pragma unroll
            for (int cc = 0; cc < 2; cc++) {
                const int r = kh * 32 + cc * 16 + l16;
                kf[ks][cc] = *reinterpret_cast<const short8*>(
                    &Kc[r * 64 + ((ks * 4 + quad) ^ (r & 7)) * 8]);
            }
        // V^T A-fragments for this key half: A[d=db*16+l16][k = kh*32 + quad*8 + j]
        short8 va[4];
#pragma unroll
        for (int db = 0; db < 4; db++) {
            const int r = db * 16 + l16;
            va[db] = *reinterpret_cast<const short8*>(
                &Vc[r * 64 + ((kh * 4 + quad) ^ (r & 7)) * 8]);
        }

#pragma unroll
        for (int q2 = 0; q2 < 2; q2++) {
            float4v s_acc[2];
#pragma unroll
            for (int cc = 0; cc < 2; cc++) s_acc[cc] = float4v{0.f, 0.f, 0.f, 0.f};
            __builtin_amdgcn_s_setprio(1);
#pragma unroll
            for (int ks = 0; ks < 2; ks++)
#pragma unroll
                for (int cc = 0; cc < 2; cc++)
                    s_acc[cc] = __builtin_amdgcn_mfma_f32_16x16x32_bf16(
                        kf[ks][cc], bq[q2][ks], s_acc[cc], 0, 0, 0);
            __builtin_amdgcn_s_setprio(0);

            // fixed-max softmax: p = 2^s. Permuted K rows make the pack
            // register-local: actual key = kh*32 + quad*8 + cc*4 + reg.
            float ls2 = 0.f;
            float p[8];
#pragma unroll
            for (int cc = 0; cc < 2; cc++)
#pragma unroll
                for (int r = 0; r < 4; r++) {
                    const float pv = __builtin_amdgcn_exp2f(s_acc[cc][r]);
                    p[cc * 4 + r] = pv;
                    ls2 += pv;
                }
            uint4v pd;
            pd.x = cvtpk(p[0], p[1]); pd.y = cvtpk(p[2], p[3]);
            pd.z = cvtpk(p[4], p[5]); pd.w = cvtpk(p[6], p[7]);
            const short8 pb = __builtin_bit_cast(short8, pd);
            l_part[q2] += ls2;
            __builtin_amdgcn_s_setprio(1);
#pragma unroll
            for (int db = 0; db < 4; db++)
                o_acc[q2][db] = __builtin_amdgcn_mfma_f32_16x16x32_bf16(
                    va[db], pb, o_acc[q2][db], 0, 0, 0);
            __builtin_amdgcn_s_setprio(0);
        }
    }

    // ---- combine key halves through LDS (K/V buffers are dead now).
    __syncthreads();                        // all waves done reading KV
    float* osh = reinterpret_cast<float*>(KV);   // 8192 floats = 32 KB exactly
    const int swz = (l16 & 7) << 2;              // 16B-granule XOR to spread banks
    if (kh == 1) {
#pragma unroll
        for (int q2 = 0; q2 < 2; q2++)
#pragma unroll
            for (int db = 0; db < 4; db++) {
                const int base = (wq * 32 + q2 * 16 + l16) * 64 + db * 16 + quad * 4;
                *reinterpret_cast<float4v*>(&osh[base ^ swz]) = o_acc[q2][db];
            }
        lsh[wq][0][lane] = l_part[0];
        lsh[wq][1][lane] = l_part[1];
    }
    __syncthreads();
    if (kh == 0) {
        const int b = bh >> 4, h = bh & 15;
#pragma unroll
        for (int q2 = 0; q2 < 2; q2++) {
            float lr = l_part[q2] + lsh[wq][q2][lane];
            lr += __shfl_xor(lr, 16, 64);
            lr += __shfl_xor(lr, 32, 64);
            const float inv = 1.f / lr;
            const int grow = b * 2048 + q0 + wq * 32 + q2 * 16 + l16;
            float sum = 0.f, s2 = 0.f;
#pragma unroll
            for (int db = 0; db < 4; db++) {
                const int base = (wq * 32 + q2 * 16 + l16) * 64 + db * 16 + quad * 4;
                const float4v oh = *reinterpret_cast<const float4v*>(&osh[base ^ swz]);
                const float o0 = (o_acc[q2][db][0] + oh[0]) * inv;
                const float o1 = (o_acc[q2][db][1] + oh[1]) * inv;
                const float o2 = (o_acc[q2][db][2] + oh[2]) * inv;
                const float o3 = (o_acc[q2][db][3] + oh[3]) * inv;
                const ushort4 st = {f2bf(o0), f2bf(o1), f2bf(o2), f2bf(o3)};
                *reinterpret_cast<ushort4*>(
                    &attn[(size_t)grow * 1024 + h * 64 + db * 16 + quad * 4]) = st;
                sum += (o0 + o1) + (o2 + o3);
                s2  += (o0 * o0 + o1 * o1) + (o2 * o2 + o3 * o3);
            }
            sum += __shfl_xor(sum, 16, 64); sum += __shfl_xor(sum, 32, 64);
            s2  += __shfl_xor(s2, 16, 64);  s2  += __shfl_xor(s2, 32, 64);
            if (quad == 0) part[(size_t)grow * 16 + h] = float2{sum, s2};
        }
    }
}

// ---------------- GEMM2: attn(bf16,raw) @ Wg^T, LN2 + rowstats fused.
// Tile 128(m) x 64(n) -> grid 512 = 2 blocks/CU.
__global__ __launch_bounds__(256) void gemm_proj(const unsigned short* __restrict__ A,
                                                 const unsigned short* __restrict__ Bt,
                                                 const float2* __restrict__ part,
                                                 const float* __restrict__ u,
                                                 const float* __restrict__ w0,
                                                 const float* __restrict__ bias,
                                                 float* __restrict__ out) {
    __shared__ unsigned short As[2 * 128 * 64];   // 32 KB
    __shared__ unsigned short Bs[2 * 64 * 64];    // 16 KB
    __shared__ float2 rstat_s[128];
    const int tid = threadIdx.x, lane = tid & 63, w = tid >> 6;
    const int quad = lane >> 4, l16 = lane & 15;
    const int ls = lane >> 3, sg = lane & 7;
    const int m0 = blockIdx.y * 128, n0 = blockIdx.x * 64;
    {   // rowstats for this block's 128 rows: 2 threads/row, 8 heads each
        const int rloc = tid >> 1, half = tid & 1;
        const float4* p4 = reinterpret_cast<const float4*>(part);
        float s = 0.f, s2 = 0.f;
#pragma unroll
        for (int j = 0; j < 4; j++) {
            const float4 p = p4[(size_t)(m0 + rloc) * 8 + half * 4 + j];
            s += p.x + p.z; s2 += p.y + p.w;
        }
        s  += __shfl_xor(s, 1, 64);
        s2 += __shfl_xor(s2, 1, 64);
        if (!half) {
            const float mu = s * (1.f / 1024.f);
            const float rstd = rsqrtf(s2 * (1.f / 1024.f) - mu * mu + 1e-5f);
            rstat_s[rloc] = float2{rstd, mu * rstd};
        }
    }   // ordered before use by the K-loop's first __syncthreads()

    float4v acc[2][4];
#pragma unroll
    for (int mi = 0; mi < 2; mi++)
#pragma unroll
        for (int ni = 0; ni < 4; ni++) acc[mi][ni] = float4v{0.f, 0.f, 0.f, 0.f};

    const int g = (sg ^ ls) * 8;
    // stage step 0
#pragma unroll
    for (int i = 0; i < 4; i++)
        gll16(&A[(size_t)(m0 + w * 32 + i * 8 + ls) * 1024 + g], &As[(w * 32 + i * 8) * 64]);
#pragma unroll
    for (int i = 0; i < 2; i++)
        gll16(&Bt[(size_t)(n0 + w * 16 + i * 8 + ls) * 1024 + g], &Bs[(w * 16 + i * 8) * 64]);

#pragma unroll 1
    for (int s = 0; s < 16; s++) {
        __syncthreads();
        if (s + 1 < 16) {
            const int k0 = (s + 1) << 6;
            unsigned short* Ad = As + (((s + 1) & 1) << 13);
            unsigned short* Bd = Bs + (((s + 1) & 1) << 12);
#pragma unroll
            for (int i = 0; i < 4; i++)
                gll16(&A[(size_t)(m0 + w * 32 + i * 8 + ls) * 1024 + k0 + g],
                      &Ad[(w * 32 + i * 8) * 64]);
#pragma unroll
            for (int i = 0; i < 2; i++)
                gll16(&Bt[(size_t)(n0 + w * 16 + i * 8 + ls) * 1024 + k0 + g],
                      &Bd[(w * 16 + i * 8) * 64]);
        }
        const unsigned short* Ac = As + ((s & 1) << 13);
        const unsigned short* Bc = Bs + ((s & 1) << 12);
#pragma unroll
        for (int ks = 0; ks < 2; ks++) {
            short8 af[2], bfr[4];
#pragma unroll
            for (int mi = 0; mi < 2; mi++) {
                const int r = w * 32 + mi * 16 + l16;
                af[mi] = *reinterpret_cast<const short8*>(
                    &Ac[r * 64 + ((ks * 4 + quad) ^ (r & 7)) * 8]);
            }
#pragma unroll
            for (int ni = 0; ni < 4; ni++) {
                const int r = ni * 16 + l16;
                bfr[ni] = *reinterpret_cast<const short8*>(
                    &Bc[r * 64 + ((ks * 4 + quad) ^ (r & 7)) * 8]);
            }
#pragma unroll
            for (int mi = 0; mi < 2; mi++)
#pragma unroll
                for (int ni = 0; ni < 4; ni++)
                    acc[mi][ni] = __builtin_amdgcn_mfma_f32_16x16x32_bf16(
                        af[mi], bfr[ni], acc[mi][ni], 0, 0, 0);
        }
    }

#pragma unroll
    for (int mi = 0; mi < 2; mi++) {
        const int rl0 = w * 32 + mi * 16 + quad * 4;
        float2 rs[4];
#pragma unroll
        for (int r = 0; r < 4; r++) rs[r] = rstat_s[rl0 + r];
#pragma unroll
        for (int ni = 0; ni < 4; ni++) {
            const int col = n0 + ni * 16 + l16;
            const float uu = u[col], ww = w0[col] + bias[col];
#pragma unroll
            for (int r = 0; r < 4; r++)
                out[(size_t)(m0 + rl0 + r) * 1024 + col] =
                    fmaf(rs[r].x, acc[mi][ni][r], ww - rs[r].y * uu);
        }
    }
}

extern "C" void kernel_launch(void* const* d_in, const int* in_sizes, int n_in,
                              void* d_out, int out_size, void* d_ws, size_t ws_size,
                              hipStream_t stream) {
    const float* x      = (const float*)d_in[0];
    const float* ln1_g  = (const float*)d_in[1];
    const float* ln1_b  = (const float*)d_in[2];
    const float* w_qk   = (const float*)d_in[3];
    const float* w_v    = (const float*)d_in[4];
    const float* ln2_g  = (const float*)d_in[5];
    const float* ln2_b  = (const float*)d_in[6];
    const float* w_proj = (const float*)d_in[7];
    const float* b_proj = (const float*)d_in[8];
    float* out = (float*)d_out;

    char* ws = (char*)d_ws;
    unsigned short* xn      = (unsigned short*)(ws + 0);         // 8MB  4096x1024 bf16
    unsigned short* wqkvT   = (unsigned short*)(ws + 8388608);   // 6MB  3072x1024 bf16
    unsigned short* wgT     = (unsigned short*)(ws + 14680064);  // 2MB  1024x1024 bf16 (g2-scaled w_proj^T)
    unsigned short* qbuf    = (unsigned short*)(ws + 16777216);  // 8MB  [32][2048][64]
    unsigned short* kbuf    = (unsigned short*)(ws + 25165824);  // 8MB  [32][2048][64]
    unsigned short* vTbuf   = (unsigned short*)(ws + 33554432);  // 8MB  [32][64][2048]
    unsigned short* attn    = (unsigned short*)(ws + 41943040);  // 8MB  4096x1024 bf16 (raw, pre-LN2)
    float2*         part    = (float2*)(ws + 50331648);          // 512KB [4096][16]
    float*          u       = (float*)(ws + 50888704);           // 4KB
    float*          w0      = (float*)(ws + 50892800);           // 4KB

    hipMemsetAsync(ws + 50888704, 0, 8192, stream);              // zero u + w0
    prep<<<8192, 256, 0, stream>>>(x, ln1_g, ln1_b, w_qk, w_v, w_proj, ln2_g, ln2_b,
                                   xn, wqkvT, wgT, u, w0);
    gemm_qkv<<<dim3(16, 32), 512, 0, stream>>>(xn, wqkvT, qbuf, kbuf, vTbuf);
    flash_attn<<<dim3(32, 16), 512, 0, stream>>>(qbuf, kbuf, vTbuf, attn, part);
    gemm_proj<<<dim3(16, 32), 256, 0, stream>>>(attn, wgT, part, u, w0, b_proj, out);
}